// Round 1
// baseline (183.899 us; speedup 1.0000x reference)
//
#include <hip/hip_runtime.h>

// x: (32,3,512,512) fp32. Per 8x8 block X (row r, col c within block),
// reference output block = D * X^T * D^T  (verified by tracing the einsum
// + transpose chain: out[r][c] = (D X D^T)[c][r]).
// One thread per 8x8 block; D staged in LDS (uniform-address broadcast reads).

#define PW 512
#define NH 64
#define NW 64

__global__ __launch_bounds__(256) void dct8x8_kernel(
    const float* __restrict__ x,
    const float* __restrict__ dct,
    float* __restrict__ out,
    int total_blocks)
{
    __shared__ float D[64];
    if (threadIdx.x < 64) D[threadIdx.x] = dct[threadIdx.x];
    __syncthreads();

    int tid = blockIdx.x * blockDim.x + threadIdx.x;
    if (tid >= total_blocks) return;

    int bw = tid & (NW - 1);          // horizontal block index
    int bh = (tid >> 6) & (NH - 1);   // vertical block index
    int bc = tid >> 12;               // fused (batch*channel) index

    size_t base = ((size_t)bc * PW + (size_t)bh * 8) * PW + (size_t)bw * 8;
    const float* src = x + base;
    float*       dst = out + base;

    // Load 8x8 block into registers: xr[r][c] = image(row r, col c) of block.
    float xr[8][8];
    #pragma unroll
    for (int r = 0; r < 8; ++r) {
        float4 a = *(const float4*)(src + (size_t)r * PW);
        float4 b = *(const float4*)(src + (size_t)r * PW + 4);
        xr[r][0] = a.x; xr[r][1] = a.y; xr[r][2] = a.z; xr[r][3] = a.w;
        xr[r][4] = b.x; xr[r][5] = b.y; xr[r][6] = b.z; xr[r][7] = b.w;
    }

    // out = D * X^T * D^T
    // Z[u][j] = sum_i D[u][i] * X^T[i][j] = sum_i D[u][i] * xr[j][i]
    // out[u][v] = sum_j Z[u][j] * D[v][j]
    #pragma unroll
    for (int u = 0; u < 8; ++u) {
        float z[8];
        #pragma unroll
        for (int j = 0; j < 8; ++j) {
            float s = 0.0f;
            #pragma unroll
            for (int i = 0; i < 8; ++i) s += D[u * 8 + i] * xr[j][i];
            z[j] = s;
        }
        float o[8];
        #pragma unroll
        for (int v = 0; v < 8; ++v) {
            float s = 0.0f;
            #pragma unroll
            for (int j = 0; j < 8; ++j) s += z[j] * D[v * 8 + j];
            o[v] = s;
        }
        *(float4*)(dst + (size_t)u * PW)     = make_float4(o[0], o[1], o[2], o[3]);
        *(float4*)(dst + (size_t)u * PW + 4) = make_float4(o[4], o[5], o[6], o[7]);
    }
}

extern "C" void kernel_launch(void* const* d_in, const int* in_sizes, int n_in,
                              void* d_out, int out_size, void* d_ws, size_t ws_size,
                              hipStream_t stream) {
    const float* x   = (const float*)d_in[0];
    const float* dct = (const float*)d_in[1];
    float* out = (float*)d_out;

    const int total_blocks = 32 * 3 * NH * NW;  // 393216
    const int block = 256;
    const int grid = (total_blocks + block - 1) / block;  // 1536
    dct8x8_kernel<<<grid, block, 0, stream>>>(x, dct, out, total_blocks);
}